// Round 2
// baseline (5067.257 us; speedup 1.0000x reference)
//
#include <hip/hip_runtime.h>

// Problem constants (fixed in the reference file)
#define GT 8192      // time steps
#define GN 1024      // state dim
#define GM 512       // input dim
#define CCH 1024     // scan chunks
#define SCH 8        // steps per chunk (CCH*SCH == GT)

// ---------------------------------------------------------------------------
// Generic fp32 tiled GEMM:
//   Out[ob + gr*ldo + gc] = alpha * sum_k A[ab + gr*lda + k] * B(k, gc)
//                           + (Cin ? beta * Cin[cb + gr*ldc + gc] : 0)
//                           + (add_id && gr==gc ? 1 : 0)
// B dense row-major: !TRANSB -> B is K x Nn (B[k*Nn + n]);
//                     TRANSB -> B is Nn x K (B[n*K + k])  => Out = A @ B^T
// M guarded; Nn multiple of 64; K multiple of 16.
// ---------------------------------------------------------------------------
template <bool TRANSB>
__global__ __launch_bounds__(256) void gemm_k(
    const float* __restrict__ A, long ab, long lda,
    const float* __restrict__ B,
    const float* __restrict__ Cin, long cb, long ldc, float beta,
    float* __restrict__ Out, long ob, long ldo,
    int M, int Nn, int K, float alpha, int add_id)
{
    __shared__ float As[16][68];   // [k][m], pad 68 keeps 16B alignment, 2-way banks (free)
    __shared__ float Bs[16][68];   // [k][n]
    const int row0 = blockIdx.x * 64;
    const int col0 = blockIdx.y * 64;
    const int tid = threadIdx.x;
    const int tx = tid & 15, ty = tid >> 4;
    float acc[4][4] = {};

    for (int k0 = 0; k0 < K; k0 += 16) {
        #pragma unroll
        for (int i = 0; i < 4; ++i) {              // A tile: 64 rows x 16 k
            int idx = tid + i * 256;
            int r = idx >> 4, c = idx & 15;
            int gr = row0 + r;
            As[c][r] = (gr < M) ? A[ab + (long)gr * lda + (k0 + c)] : 0.f;
        }
        if (!TRANSB) {
            #pragma unroll
            for (int i = 0; i < 4; ++i) {          // B tile: 16 k x 64 n
                int idx = tid + i * 256;
                int r = idx >> 6, c = idx & 63;
                Bs[r][c] = B[(long)(k0 + r) * Nn + (col0 + c)];
            }
        } else {
            #pragma unroll
            for (int i = 0; i < 4; ++i) {          // B tile from Nn x K layout
                int idx = tid + i * 256;
                int r = idx >> 4, c = idx & 15;
                Bs[c][r] = B[(long)(col0 + r) * K + (k0 + c)];
            }
        }
        __syncthreads();
        #pragma unroll
        for (int k = 0; k < 16; ++k) {
            float a[4], b[4];
            #pragma unroll
            for (int i = 0; i < 4; ++i) a[i] = As[k][ty * 4 + i];
            #pragma unroll
            for (int j = 0; j < 4; ++j) b[j] = Bs[k][tx * 4 + j];
            #pragma unroll
            for (int i = 0; i < 4; ++i)
                #pragma unroll
                for (int j = 0; j < 4; ++j)
                    acc[i][j] += a[i] * b[j];
        }
        __syncthreads();
    }

    #pragma unroll
    for (int i = 0; i < 4; ++i) {
        int gr = row0 + ty * 4 + i;
        if (gr >= M) continue;
        #pragma unroll
        for (int j = 0; j < 4; ++j) {
            int gc = col0 + tx * 4 + j;
            float v = alpha * acc[i][j];
            if (Cin) v += beta * Cin[cb + (long)gr * ldc + gc];
            if (add_id && gr == gc) v += 1.f;
            Out[ob + (long)gr * ldo + gc] = v;
        }
    }
}

// dst[db + r*ds + c] = src[sb + r*ss + c]
__global__ void copy_rows_k(float* __restrict__ dst, long db, long ds,
                            const float* __restrict__ src, long sb, long ss, int ncols)
{
    int r = blockIdx.y;
    int c = blockIdx.x * 256 + threadIdx.x;
    if (c < ncols) dst[db + (long)r * ds + c] = src[sb + (long)r * ss + c];
}

// dst[db + r*ds + c] += src[r*ncols + c]
__global__ void add_rows_k(float* __restrict__ dst, long db, long ds,
                           const float* __restrict__ src, int ncols)
{
    int r = blockIdx.y;
    int c = blockIdx.x * 256 + threadIdx.x;
    if (c < ncols) dst[db + (long)r * ds + c] += src[(long)r * ncols + c];
}

// dst = s*src + I   (n x n)
__global__ void scale_add_id_k(float* __restrict__ dst, const float* __restrict__ src,
                               float s, int n)
{
    int r = blockIdx.y;
    int c = blockIdx.x * 256 + threadIdx.x;
    if (c < n) dst[(long)r * n + c] = s * src[(long)r * n + c] + ((r == c) ? 1.f : 0.f);
}

// dst = s*src (flat)
__global__ void scale_copy_k(float* __restrict__ dst, const float* __restrict__ src,
                             float s, long cnt)
{
    long i = (long)blockIdx.x * 256 + threadIdx.x;
    if (i < cnt) dst[i] = s * src[i];
}

// G1 = h*(V1 - V2); G2 = h*V2
__global__ void g1g2_k(float* __restrict__ g1, float* __restrict__ g2,
                       const float* __restrict__ v1, const float* __restrict__ v2,
                       float h, long cnt)
{
    long i = (long)blockIdx.x * 256 + threadIdx.x;
    if (i < cnt) {
        float a = v1[i], b = v2[i];
        g1[i] = h * (a - b);
        g2[i] = h * b;
    }
}

extern "C" void kernel_launch(void* const* d_in, const int* in_sizes, int n_in,
                              void* d_out, int out_size, void* d_ws, size_t ws_size,
                              hipStream_t stream)
{
    (void)in_sizes; (void)n_in; (void)out_size; (void)ws_size;
    const float* y0 = (const float*)d_in[1];
    const float* u  = (const float*)d_in[2];
    const float* Am = (const float*)d_in[3];
    const float* Bm = (const float*)d_in[4];
    float* Yout = (float*)d_out;               // (GT x GN) fp32
    float* w = (float*)d_ws;

    const float h = 0.01f;                     // ts[1]-ts[0] in fp32 (DT fixed by problem)
    const int N = GN;

    // ws layout (floats): 3*1M + 3*0.5M + 2*0.5M + 2*1M = 7.5M floats = 30 MB
    float* Eyy = w;
    float* T1  = Eyy + (long)N * N;
    float* T2  = T1  + (long)N * N;
    float* V1  = T2  + (long)N * N;
    float* Vt  = V1  + (long)N * GM;
    float* V2  = Vt  + (long)N * GM;
    float* G1  = V2  + (long)N * GM;
    float* G2  = G1  + (long)N * GM;
    float* Z   = G2  + (long)N * GM;
    float* Zt  = Z   + (long)CCH * N;

    dim3 blk(256);

    auto gemm = [&](bool transb, const float* A, long ab, long lda,
                    const float* B,
                    const float* Cin, long cb, long ldc, float beta,
                    float* Out, long ob, long ldo,
                    int M, int Nn, int K, float alpha, int add_id) {
        dim3 grid((M + 63) / 64, Nn / 64);
        if (transb)
            gemm_k<true><<<grid, blk, 0, stream>>>(A, ab, lda, B, Cin, cb, ldc, beta,
                                                   Out, ob, ldo, M, Nn, K, alpha, add_id);
        else
            gemm_k<false><<<grid, blk, 0, stream>>>(A, ab, lda, B, Cin, cb, ldc, beta,
                                                    Out, ob, ldo, M, Nn, K, alpha, add_id);
    };

    // ---- Eyy = exp(h*A): Horner Taylor K=5 (||Ah|| ~ 0.007 -> trunc ~1e-16) ----
    scale_add_id_k<<<dim3(4, N), blk, 0, stream>>>(T1, Am, h / 5.f, N);  // P = I + X/5
    {
        float* pc = T1; float* pn = T2;
        for (int k = 4; k >= 1; --k) {
            float* out = (k == 1) ? Eyy : pn;
            // P = I + (h/k) * A @ P
            gemm(false, Am, 0, N, pc, nullptr, 0, 0, 0.f, out, 0, N, N, N, N, h / (float)k, 1);
            pn = pc; pc = out;
        }
    }

    // ---- V1 = phi1(X) B, V2 = phi2(X) B (Horner K=4) ----
    const long NM = (long)N * GM;
    scale_copy_k<<<dim3((unsigned)((NM + 255) / 256)), blk, 0, stream>>>(V1, Bm, 1.f / 120.f, NM);
    {
        const float f1[4] = {1.f / 24.f, 1.f / 6.f, 0.5f, 1.f};   // 1/(j+1)!, j=3..0
        float* pc = V1; float* pn = Vt;
        for (int j = 3; j >= 0; --j) {
            // V = h*A@V + B/(j+1)!
            gemm(false, Am, 0, N, pc, Bm, 0, GM, f1[3 - j], pn, 0, GM, N, GM, N, h, 0);
            float* t = pc; pc = pn; pn = t;
        }  // ends in V1 (4 swaps)
    }
    scale_copy_k<<<dim3((unsigned)((NM + 255) / 256)), blk, 0, stream>>>(V2, Bm, 1.f / 720.f, NM);
    {
        const float f2[4] = {1.f / 120.f, 1.f / 24.f, 1.f / 6.f, 0.5f}; // 1/(j+2)!, j=3..0
        float* pc = V2; float* pn = Vt;
        for (int j = 3; j >= 0; --j) {
            gemm(false, Am, 0, N, pc, Bm, 0, GM, f2[3 - j], pn, 0, GM, N, GM, N, h, 0);
            float* t = pc; pc = pn; pn = t;
        }  // ends in V2
    }

    // ---- G1 = h*(V1 - V2), G2 = h*V2 ----
    g1g2_k<<<dim3((unsigned)((NM + 255) / 256)), blk, 0, stream>>>(G1, G2, V1, V2, h, NM);

    // ---- stage c into Yout rows 1..GT-1:  c_t = u_{t-1} @ G1^T + u_t @ G2^T ----
    gemm(true, u, 0, GM, G1, nullptr, 0, 0, 0.f, Yout, (long)N, N, GT - 1, N, GM, 1.f, 0);
    gemm(true, u, GM, GM, G2, Yout, (long)N, N, 1.f, Yout, (long)N, N, GT - 1, N, GM, 1.f, 0);

    // Yout[0] = y0
    copy_rows_k<<<dim3(4, 1), blk, 0, stream>>>(Yout, 0, 0, y0, 0, 0, N);

    // ---- Phase 1: within-chunk zero-init responses, in place in Yout ----
    // chunk i holds rows iS+1 .. iS+S ; step s: w_t = E w_{t-1} + c_{t-1}; s=1 is identity.
    for (int s = 2; s <= SCH; ++s) {
        int Mr = (GT - 1 - s) / SCH + 1;
        gemm(true, Yout, (long)(s - 1) * N, (long)SCH * N, Eyy,
             Yout, (long)s * N, (long)SCH * N, 1.f,
             Yout, (long)s * N, (long)SCH * N, Mr, N, N, 1.f, 0);
    }

    // ---- Phase 2: boundary states z_i via doubling with shared matrix E^S ----
    // Z[0] = y0, Z[i] = d_{i-1} = Yout[i*S]
    copy_rows_k<<<dim3(4, 1), blk, 0, stream>>>(Z, 0, 0, y0, 0, 0, N);
    copy_rows_k<<<dim3(4, CCH - 1), blk, 0, stream>>>(Z, (long)N, (long)N,
                                                      Yout, (long)SCH * N, (long)SCH * N, N);
    // E^8 via squaring: T1=E^2, T2=E^4, T1=E^8
    gemm(false, Eyy, 0, N, Eyy, nullptr, 0, 0, 0.f, T1, 0, N, N, N, N, 1.f, 0);
    gemm(false, T1, 0, N, T1, nullptr, 0, 0, 0.f, T2, 0, N, N, N, N, 1.f, 0);
    gemm(false, T2, 0, N, T2, nullptr, 0, 0, 0.f, T1, 0, N, N, N, N, 1.f, 0);
    {
        float* Mc = T1; float* Mo = T2;
        float* Zc = Z;  float* Zn = Zt;
        for (int p = 0; p < 10; ++p) {           // log2(CCH) = 10 rounds, exact
            int o = 1 << p;
            // Zn[i] = Zc[i] + Mc @ Zc[i-o]  for i in [o, CCH)
            gemm(true, Zc, 0, N, Mc, Zc, (long)o * N, N, 1.f,
                 Zn, (long)o * N, N, CCH - o, N, N, 1.f, 0);
            copy_rows_k<<<dim3(4, o), blk, 0, stream>>>(Zn, 0, N, Zc, 0, N, N);
            if (p < 9) {                          // Mc = Mc^2
                gemm(false, Mc, 0, N, Mc, nullptr, 0, 0, 0.f, Mo, 0, N, N, N, N, 1.f, 0);
                float* t = Mc; Mc = Mo; Mo = t;
            }
            float* t = Zc; Zc = Zn; Zn = t;
        }
        // ---- Phase 3: y_{iS} = z_i (exact, incl. boundary rows s=8) ;
        //      y_{iS+s} = w + E^s z_i for s=1..7 ONLY.
        // Rows with s=8 ARE the boundary rows (i+1)*S — already exact from the
        // z-copy; adding E^8 z_i there would double-count the homogeneous part
        // (that was the round-1 bug, absmax ~3.3).
        copy_rows_k<<<dim3(4, CCH), blk, 0, stream>>>(Yout, 0, (long)SCH * N, Zc, 0, N, N);
        float* Q = Zc; float* Qt = Zn;            // Q holds E^s z_i
        for (int s = 1; s <= SCH - 1; ++s) {
            gemm(true, Q, 0, N, Eyy, nullptr, 0, 0, 0.f, Qt, 0, N, CCH, N, N, 1.f, 0);
            int Mr = (GT - 1 - s) / SCH + 1;
            add_rows_k<<<dim3(4, Mr), blk, 0, stream>>>(Yout, (long)s * N, (long)SCH * N, Qt, N);
            float* t = Q; Q = Qt; Qt = t;
        }
    }
}

// Round 3
// 3561.278 us; speedup vs baseline: 1.4229x; 1.4229x over previous
//
#include <hip/hip_runtime.h>

// Problem constants (fixed in the reference file)
#define GT 8192      // time steps
#define GN 1024      // state dim
#define GM 512       // input dim
#define CCH 1024     // scan chunks
#define SCH 8        // steps per chunk (CCH*SCH == GT)

typedef __attribute__((ext_vector_type(8))) short bf16x8;
typedef __attribute__((ext_vector_type(4))) float f32x4;

__device__ __forceinline__ unsigned short f2bf(float x) {   // RNE fp32->bf16
    unsigned int u = __float_as_uint(x);
    u += 0x7FFF + ((u >> 16) & 1);
    return (unsigned short)(u >> 16);
}
__device__ __forceinline__ float bf2f(unsigned short b) {
    return __uint_as_float(((unsigned int)b) << 16);
}
// triple split: x ~= s0 + s1 + s2 (24+ significand bits, residuals exact in f32)
__device__ __forceinline__ void split3(float x, unsigned short& s0,
                                       unsigned short& s1, unsigned short& s2) {
    s0 = f2bf(x); float r = x - bf2f(s0);
    s1 = f2bf(r); r -= bf2f(s1);
    s2 = f2bf(r);
}

// ---------------------------------------------------------------------------
// Split-bf16 MFMA GEMM (fp32-equivalent accuracy via 6 limb-products):
//   Out[ob + gr*ldo + gc] = alpha * sum_k A[ab+gr*lda+k] * B(k,gc)
//                           + (Cin ? beta*Cin[cb+gr*ldc+gc] : 0)
//                           + (add_id && gr==gc ? 1 : 0)
// !TRANSB: B is K x Nn row-major.  TRANSB: B is Nn x K row-major (Out=A@B^T).
// M guarded; Nn % BN == 0; K % 32 == 0. 256 threads = 4 waves (2x2), each
// wave computes (BM/2)x(BN/2) via 16x16x32 bf16 MFMA.
// ---------------------------------------------------------------------------
template <int BM, int BN, bool TRANSB>
__global__ __launch_bounds__(256) void gemm_mfma(
    const float* __restrict__ A, long ab, long lda,
    const float* __restrict__ B,
    const float* __restrict__ Cin, long cb, long ldc, float beta,
    float* __restrict__ Out, long ob, long ldo,
    int M, int Nn, int K, float alpha, int add_id)
{
    constexpr int LDT = 40;                    // ushorts/row: 80 B, 16B-aligned
    __shared__ unsigned short At[3][BM][LDT];  // [limb][m][k]
    __shared__ unsigned short Bt[3][BN][LDT];  // [limb][n][k]

    const int tid = threadIdx.x;
    const int lane = tid & 63;
    const int wid = tid >> 6;
    const int row0 = blockIdx.x * BM;
    const int col0 = blockIdx.y * BN;

    constexpr int MR = BM / 32;                // 16-row tiles per wave
    constexpr int NR = BN / 32;
    const int wrow = (wid >> 1) * (BM / 2);
    const int wcol = (wid & 1) * (BN / 2);
    const int l16 = lane & 15;
    const int koff = lane >> 4;                // 0..3 -> k-block of 8

    f32x4 acc[MR][NR] = {};

    for (int k0 = 0; k0 < K; k0 += 32) {
        // ---- stage A tile: BM x 32 fp32 -> 3 limb tiles ----
        #pragma unroll
        for (int p = 0; p < BM / 32; ++p) {
            int r = p * 32 + (tid >> 3);
            int kl = (tid & 7) * 4;
            int gr = row0 + r;
            float4 v = make_float4(0.f, 0.f, 0.f, 0.f);
            if (gr < M) v = *(const float4*)&A[ab + (long)gr * lda + (k0 + kl)];
            unsigned short h0[4], h1[4], h2[4];
            split3(v.x, h0[0], h1[0], h2[0]);
            split3(v.y, h0[1], h1[1], h2[1]);
            split3(v.z, h0[2], h1[2], h2[2]);
            split3(v.w, h0[3], h1[3], h2[3]);
            *(ushort4*)&At[0][r][kl] = make_ushort4(h0[0], h0[1], h0[2], h0[3]);
            *(ushort4*)&At[1][r][kl] = make_ushort4(h1[0], h1[1], h1[2], h1[3]);
            *(ushort4*)&At[2][r][kl] = make_ushort4(h2[0], h2[1], h2[2], h2[3]);
        }
        // ---- stage B tile -> Bt[limb][n][k] ----
        if (TRANSB) {                          // B: Nn x K, direct rows
            #pragma unroll
            for (int p = 0; p < BN / 32; ++p) {
                int r = p * 32 + (tid >> 3);
                int kl = (tid & 7) * 4;
                float4 v = *(const float4*)&B[(long)(col0 + r) * K + (k0 + kl)];
                unsigned short h0[4], h1[4], h2[4];
                split3(v.x, h0[0], h1[0], h2[0]);
                split3(v.y, h0[1], h1[1], h2[1]);
                split3(v.z, h0[2], h1[2], h2[2]);
                split3(v.w, h0[3], h1[3], h2[3]);
                *(ushort4*)&Bt[0][r][kl] = make_ushort4(h0[0], h0[1], h0[2], h0[3]);
                *(ushort4*)&Bt[1][r][kl] = make_ushort4(h1[0], h1[1], h1[2], h1[3]);
                *(ushort4*)&Bt[2][r][kl] = make_ushort4(h2[0], h2[1], h2[2], h2[3]);
            }
        } else {                               // B: K x Nn, transpose-scatter
            constexpr int TPK = BN / 4;        // threads per k-row
            #pragma unroll
            for (int p = 0; p < BN / 32; ++p) {
                int kl = p * (256 / TPK) + tid / TPK;
                int nl = (tid % TPK) * 4;
                float4 v = *(const float4*)&B[(long)(k0 + kl) * Nn + (col0 + nl)];
                unsigned short s0, s1, s2;
                split3(v.x, s0, s1, s2);
                Bt[0][nl + 0][kl] = s0; Bt[1][nl + 0][kl] = s1; Bt[2][nl + 0][kl] = s2;
                split3(v.y, s0, s1, s2);
                Bt[0][nl + 1][kl] = s0; Bt[1][nl + 1][kl] = s1; Bt[2][nl + 1][kl] = s2;
                split3(v.z, s0, s1, s2);
                Bt[0][nl + 2][kl] = s0; Bt[1][nl + 2][kl] = s1; Bt[2][nl + 2][kl] = s2;
                split3(v.w, s0, s1, s2);
                Bt[0][nl + 3][kl] = s0; Bt[1][nl + 3][kl] = s1; Bt[2][nl + 3][kl] = s2;
            }
        }
        __syncthreads();

        // ---- compute: 6 limb-products per fragment pair ----
        bf16x8 bf[NR][3];
        #pragma unroll
        for (int nr = 0; nr < NR; ++nr) {
            int brow = wcol + nr * 16 + l16;
            #pragma unroll
            for (int s = 0; s < 3; ++s)
                bf[nr][s] = *(const bf16x8*)&Bt[s][brow][koff * 8];
        }
        #pragma unroll
        for (int mr = 0; mr < MR; ++mr) {
            int arow = wrow + mr * 16 + l16;
            bf16x8 a0 = *(const bf16x8*)&At[0][arow][koff * 8];
            bf16x8 a1 = *(const bf16x8*)&At[1][arow][koff * 8];
            bf16x8 a2 = *(const bf16x8*)&At[2][arow][koff * 8];
            #pragma unroll
            for (int nr = 0; nr < NR; ++nr) {
                f32x4 c = acc[mr][nr];
                c = __builtin_amdgcn_mfma_f32_16x16x32_bf16(a0, bf[nr][0], c, 0, 0, 0);
                c = __builtin_amdgcn_mfma_f32_16x16x32_bf16(a0, bf[nr][1], c, 0, 0, 0);
                c = __builtin_amdgcn_mfma_f32_16x16x32_bf16(a1, bf[nr][0], c, 0, 0, 0);
                c = __builtin_amdgcn_mfma_f32_16x16x32_bf16(a0, bf[nr][2], c, 0, 0, 0);
                c = __builtin_amdgcn_mfma_f32_16x16x32_bf16(a1, bf[nr][1], c, 0, 0, 0);
                c = __builtin_amdgcn_mfma_f32_16x16x32_bf16(a2, bf[nr][0], c, 0, 0, 0);
                acc[mr][nr] = c;
            }
        }
        __syncthreads();
    }

    // ---- epilogue: D[reg r] -> row=(lane>>4)*4+r, col=lane&15 (m89-verified) ----
    #pragma unroll
    for (int mr = 0; mr < MR; ++mr) {
        #pragma unroll
        for (int r = 0; r < 4; ++r) {
            int gr = row0 + wrow + mr * 16 + koff * 4 + r;
            if (gr >= M) continue;
            #pragma unroll
            for (int nr = 0; nr < NR; ++nr) {
                int gc = col0 + wcol + nr * 16 + l16;
                float v = alpha * acc[mr][nr][r];
                if (Cin) v += beta * Cin[cb + (long)gr * ldc + gc];
                if (add_id && gr == gc) v += 1.f;
                Out[ob + (long)gr * ldo + gc] = v;
            }
        }
    }
}

// dst[db + r*ds + c] = src[sb + r*ss + c]
__global__ void copy_rows_k(float* __restrict__ dst, long db, long ds,
                            const float* __restrict__ src, long sb, long ss, int ncols)
{
    int r = blockIdx.y;
    int c = blockIdx.x * 256 + threadIdx.x;
    if (c < ncols) dst[db + (long)r * ds + c] = src[sb + (long)r * ss + c];
}

// dst[db + r*ds + c] += src[r*ncols + c]
__global__ void add_rows_k(float* __restrict__ dst, long db, long ds,
                           const float* __restrict__ src, int ncols)
{
    int r = blockIdx.y;
    int c = blockIdx.x * 256 + threadIdx.x;
    if (c < ncols) dst[db + (long)r * ds + c] += src[(long)r * ncols + c];
}

// dst = s*src + I   (n x n)
__global__ void scale_add_id_k(float* __restrict__ dst, const float* __restrict__ src,
                               float s, int n)
{
    int r = blockIdx.y;
    int c = blockIdx.x * 256 + threadIdx.x;
    if (c < n) dst[(long)r * n + c] = s * src[(long)r * n + c] + ((r == c) ? 1.f : 0.f);
}

// dst = s*src (flat)
__global__ void scale_copy_k(float* __restrict__ dst, const float* __restrict__ src,
                             float s, long cnt)
{
    long i = (long)blockIdx.x * 256 + threadIdx.x;
    if (i < cnt) dst[i] = s * src[i];
}

// G1 = h*(V1 - V2); G2 = h*V2
__global__ void g1g2_k(float* __restrict__ g1, float* __restrict__ g2,
                       const float* __restrict__ v1, const float* __restrict__ v2,
                       float h, long cnt)
{
    long i = (long)blockIdx.x * 256 + threadIdx.x;
    if (i < cnt) {
        float a = v1[i], b = v2[i];
        g1[i] = h * (a - b);
        g2[i] = h * b;
    }
}

extern "C" void kernel_launch(void* const* d_in, const int* in_sizes, int n_in,
                              void* d_out, int out_size, void* d_ws, size_t ws_size,
                              hipStream_t stream)
{
    (void)in_sizes; (void)n_in; (void)out_size; (void)ws_size;
    const float* y0 = (const float*)d_in[1];
    const float* u  = (const float*)d_in[2];
    const float* Am = (const float*)d_in[3];
    const float* Bm = (const float*)d_in[4];
    float* Yout = (float*)d_out;               // (GT x GN) fp32
    float* w = (float*)d_ws;

    const float h = 0.01f;
    const int N = GN;

    float* Eyy = w;
    float* T1  = Eyy + (long)N * N;
    float* T2  = T1  + (long)N * N;
    float* V1  = T2  + (long)N * N;
    float* Vt  = V1  + (long)N * GM;
    float* V2  = Vt  + (long)N * GM;
    float* G1  = V2  + (long)N * GM;
    float* G2  = G1  + (long)N * GM;
    float* Z   = G2  + (long)N * GM;
    float* Zt  = Z   + (long)CCH * N;

    dim3 blk(256);

    auto gemm = [&](bool transb, const float* A, long ab, long lda,
                    const float* B,
                    const float* Cin, long cb, long ldc, float beta,
                    float* Out, long ob, long ldo,
                    int M, int Nn, int K, float alpha, int add_id) {
        if (M > 1536 && (Nn % 128) == 0) {
            dim3 grid((M + 127) / 128, Nn / 128);
            if (transb)
                gemm_mfma<128, 128, true><<<grid, blk, 0, stream>>>(A, ab, lda, B, Cin, cb, ldc, beta, Out, ob, ldo, M, Nn, K, alpha, add_id);
            else
                gemm_mfma<128, 128, false><<<grid, blk, 0, stream>>>(A, ab, lda, B, Cin, cb, ldc, beta, Out, ob, ldo, M, Nn, K, alpha, add_id);
        } else {
            dim3 grid((M + 63) / 64, Nn / 64);
            if (transb)
                gemm_mfma<64, 64, true><<<grid, blk, 0, stream>>>(A, ab, lda, B, Cin, cb, ldc, beta, Out, ob, ldo, M, Nn, K, alpha, add_id);
            else
                gemm_mfma<64, 64, false><<<grid, blk, 0, stream>>>(A, ab, lda, B, Cin, cb, ldc, beta, Out, ob, ldo, M, Nn, K, alpha, add_id);
        }
    };

    // ---- Eyy = exp(h*A): Horner Taylor K=5 ----
    scale_add_id_k<<<dim3(4, N), blk, 0, stream>>>(T1, Am, h / 5.f, N);
    {
        float* pc = T1; float* pn = T2;
        for (int k = 4; k >= 1; --k) {
            float* out = (k == 1) ? Eyy : pn;
            gemm(false, Am, 0, N, pc, nullptr, 0, 0, 0.f, out, 0, N, N, N, N, h / (float)k, 1);
            pn = pc; pc = out;
        }
    }

    // ---- V1 = phi1(X) B, V2 = phi2(X) B (Horner K=4) ----
    const long NM = (long)N * GM;
    scale_copy_k<<<dim3((unsigned)((NM + 255) / 256)), blk, 0, stream>>>(V1, Bm, 1.f / 120.f, NM);
    {
        const float f1[4] = {1.f / 24.f, 1.f / 6.f, 0.5f, 1.f};
        float* pc = V1; float* pn = Vt;
        for (int j = 3; j >= 0; --j) {
            gemm(false, Am, 0, N, pc, Bm, 0, GM, f1[3 - j], pn, 0, GM, N, GM, N, h, 0);
            float* t = pc; pc = pn; pn = t;
        }
    }
    scale_copy_k<<<dim3((unsigned)((NM + 255) / 256)), blk, 0, stream>>>(V2, Bm, 1.f / 720.f, NM);
    {
        const float f2[4] = {1.f / 120.f, 1.f / 24.f, 1.f / 6.f, 0.5f};
        float* pc = V2; float* pn = Vt;
        for (int j = 3; j >= 0; --j) {
            gemm(false, Am, 0, N, pc, Bm, 0, GM, f2[3 - j], pn, 0, GM, N, GM, N, h, 0);
            float* t = pc; pc = pn; pn = t;
        }
    }

    // ---- G1 = h*(V1 - V2), G2 = h*V2 ----
    g1g2_k<<<dim3((unsigned)((NM + 255) / 256)), blk, 0, stream>>>(G1, G2, V1, V2, h, NM);

    // ---- stage c into Yout rows 1..GT-1 ----
    gemm(true, u, 0, GM, G1, nullptr, 0, 0, 0.f, Yout, (long)N, N, GT - 1, N, GM, 1.f, 0);
    gemm(true, u, GM, GM, G2, Yout, (long)N, N, 1.f, Yout, (long)N, N, GT - 1, N, GM, 1.f, 0);

    // Yout[0] = y0
    copy_rows_k<<<dim3(4, 1), blk, 0, stream>>>(Yout, 0, 0, y0, 0, 0, N);

    // ---- Phase 1: within-chunk zero-init responses, in place in Yout ----
    for (int s = 2; s <= SCH; ++s) {
        int Mr = (GT - 1 - s) / SCH + 1;
        gemm(true, Yout, (long)(s - 1) * N, (long)SCH * N, Eyy,
             Yout, (long)s * N, (long)SCH * N, 1.f,
             Yout, (long)s * N, (long)SCH * N, Mr, N, N, 1.f, 0);
    }

    // ---- Phase 2: boundary states via doubling with E^8 ----
    copy_rows_k<<<dim3(4, 1), blk, 0, stream>>>(Z, 0, 0, y0, 0, 0, N);
    copy_rows_k<<<dim3(4, CCH - 1), blk, 0, stream>>>(Z, (long)N, (long)N,
                                                      Yout, (long)SCH * N, (long)SCH * N, N);
    gemm(false, Eyy, 0, N, Eyy, nullptr, 0, 0, 0.f, T1, 0, N, N, N, N, 1.f, 0);
    gemm(false, T1, 0, N, T1, nullptr, 0, 0, 0.f, T2, 0, N, N, N, N, 1.f, 0);
    gemm(false, T2, 0, N, T2, nullptr, 0, 0, 0.f, T1, 0, N, N, N, N, 1.f, 0);
    {
        float* Mc = T1; float* Mo = T2;
        float* Zc = Z;  float* Zn = Zt;
        for (int p = 0; p < 10; ++p) {
            int o = 1 << p;
            gemm(true, Zc, 0, N, Mc, Zc, (long)o * N, N, 1.f,
                 Zn, (long)o * N, N, CCH - o, N, N, 1.f, 0);
            copy_rows_k<<<dim3(4, o), blk, 0, stream>>>(Zn, 0, N, Zc, 0, N, N);
            if (p < 9) {
                gemm(false, Mc, 0, N, Mc, nullptr, 0, 0, 0.f, Mo, 0, N, N, N, N, 1.f, 0);
                float* t = Mc; Mc = Mo; Mo = t;
            }
            float* t = Zc; Zc = Zn; Zn = t;
        }
        // ---- Phase 3: y_{iS} = z_i exact; y_{iS+s} += E^s z_i for s=1..7 only ----
        copy_rows_k<<<dim3(4, CCH), blk, 0, stream>>>(Yout, 0, (long)SCH * N, Zc, 0, N, N);
        float* Q = Zc; float* Qt = Zn;
        for (int s = 1; s <= SCH - 1; ++s) {
            gemm(true, Q, 0, N, Eyy, nullptr, 0, 0, 0.f, Qt, 0, N, CCH, N, N, 1.f, 0);
            int Mr = (GT - 1 - s) / SCH + 1;
            add_rows_k<<<dim3(4, Mr), blk, 0, stream>>>(Yout, (long)s * N, (long)SCH * N, Qt, N);
            float* t = Q; Q = Qt; Qt = t;
        }
    }
}

// Round 4
// 1371.048 us; speedup vs baseline: 3.6959x; 2.5975x over previous
//
#include <hip/hip_runtime.h>

// Problem constants (fixed in the reference file)
#define GT 8192      // time steps
#define GN 1024      // state dim
#define GM 512       // input dim
#define CCH 1024     // scan chunks
#define SCH 8        // steps per chunk (CCH*SCH == GT)
#define PLSZ (1024*1024)   // elements per limb plane (all plane sets are 1024x1024)

typedef __attribute__((ext_vector_type(8))) short bf16x8;
typedef __attribute__((ext_vector_type(4))) float f32x4;
typedef __attribute__((ext_vector_type(4))) unsigned short u16x4;
typedef __attribute__((ext_vector_type(8))) unsigned short u16x8;

__device__ __forceinline__ unsigned short f2bf(float x) {   // RNE fp32->bf16
    unsigned int u = __float_as_uint(x);
    u += 0x7FFF + ((u >> 16) & 1);
    return (unsigned short)(u >> 16);
}
__device__ __forceinline__ float bf2f(unsigned short b) {
    return __uint_as_float(((unsigned int)b) << 16);
}
__device__ __forceinline__ void split2(float x, unsigned short& h0, unsigned short& h1) {
    h0 = f2bf(x);
    h1 = f2bf(x - bf2f(h0));
}
// triple split (fallback path)
__device__ __forceinline__ void split3(float x, unsigned short& s0,
                                       unsigned short& s1, unsigned short& s2) {
    s0 = f2bf(x); float r = x - bf2f(s0);
    s1 = f2bf(r); r -= bf2f(s1);
    s2 = f2bf(r);
}

// ---------------------------------------------------------------------------
// FAST-PATH GEMM: Out = alpha * Dyn @ S^T (+ beta*Cin) (+I), K=1024, Nn=1024.
// S = 2 bf16 limb planes, row-major [1024][1024]; limb1 at Spl+PLSZ.
// Dyn = fp32 rows (split2 on the fly). 512 threads = 8 waves: waves 0-3 take
// k-low half of each 64-k step, waves 4-7 k-high; 2x2 quads of 32x32 output.
// Out2 (optional) gets the PURE product alpha*acc (before Cin) — phase-3 Q.
// ---------------------------------------------------------------------------
__global__ __launch_bounds__(512) void gemm_ps(
    const float* __restrict__ Dyn, long ab, long lda,
    const unsigned short* __restrict__ Spl,
    const float* __restrict__ Cin, long cb, long ldc, float beta,
    float* __restrict__ Out, long ob, long ldo,
    float* __restrict__ Out2, long ob2, long ldo2,
    int M, float alpha, int add_id)
{
    __shared__ unsigned short Ap[2][64][72];   // [limb][row][k], 144B rows (16B mult)
    __shared__ unsigned short Bp[2][64][72];

    const int tid = threadIdx.x;
    const int lane = tid & 63;
    const int w = tid >> 6;            // 0..7
    const int ksub = w >> 2;           // 0/1 -> k half
    const int quad = w & 3;
    const int wrow = (quad >> 1) * 32, wcol = (quad & 1) * 32;
    const int l16 = lane & 15, koff = lane >> 4;
    const int row0 = blockIdx.x * 64, col0 = blockIdx.y * 64;

    const int srow = tid >> 3;         // staging: row 0..63
    const int skq = (tid & 7) * 8;     // staging: k offset 0..56

    f32x4 acc[2][2] = {};

    for (int k0 = 0; k0 < 1024; k0 += 64) {
        // ---- stage A (fp32 -> 2 limbs) ----
        {
            int gr = row0 + srow;
            float4 v0 = make_float4(0.f,0.f,0.f,0.f), v1 = v0;
            if (gr < M) {
                const float* p = &Dyn[ab + (long)gr * lda + k0 + skq];
                v0 = *(const float4*)p;
                v1 = *(const float4*)(p + 4);
            }
            u16x4 l0a, l1a, l0b, l1b;
            split2(v0.x, ((unsigned short*)&l0a)[0], ((unsigned short*)&l1a)[0]);
            split2(v0.y, ((unsigned short*)&l0a)[1], ((unsigned short*)&l1a)[1]);
            split2(v0.z, ((unsigned short*)&l0a)[2], ((unsigned short*)&l1a)[2]);
            split2(v0.w, ((unsigned short*)&l0a)[3], ((unsigned short*)&l1a)[3]);
            split2(v1.x, ((unsigned short*)&l0b)[0], ((unsigned short*)&l1b)[0]);
            split2(v1.y, ((unsigned short*)&l0b)[1], ((unsigned short*)&l1b)[1]);
            split2(v1.z, ((unsigned short*)&l0b)[2], ((unsigned short*)&l1b)[2]);
            split2(v1.w, ((unsigned short*)&l0b)[3], ((unsigned short*)&l1b)[3]);
            *(u16x4*)&Ap[0][srow][skq]     = l0a;
            *(u16x4*)&Ap[0][srow][skq + 4] = l0b;
            *(u16x4*)&Ap[1][srow][skq]     = l1a;
            *(u16x4*)&Ap[1][srow][skq + 4] = l1b;
        }
        // ---- stage B (plane copy) ----
        {
            const unsigned short* p0 = &Spl[(long)(col0 + srow) * 1024 + k0 + skq];
            *(u16x8*)&Bp[0][srow][skq] = *(const u16x8*)p0;
            *(u16x8*)&Bp[1][srow][skq] = *(const u16x8*)(p0 + PLSZ);
        }
        __syncthreads();

        const int kw = ksub * 32 + koff * 8;
        bf16x8 a0[2], a1[2], b0[2], b1[2];
        #pragma unroll
        for (int mr = 0; mr < 2; ++mr) {
            a0[mr] = *(const bf16x8*)&Ap[0][wrow + mr * 16 + l16][kw];
            a1[mr] = *(const bf16x8*)&Ap[1][wrow + mr * 16 + l16][kw];
        }
        #pragma unroll
        for (int nr = 0; nr < 2; ++nr) {
            b0[nr] = *(const bf16x8*)&Bp[0][wcol + nr * 16 + l16][kw];
            b1[nr] = *(const bf16x8*)&Bp[1][wcol + nr * 16 + l16][kw];
        }
        #pragma unroll
        for (int mr = 0; mr < 2; ++mr)
            #pragma unroll
            for (int nr = 0; nr < 2; ++nr) {
                f32x4 c = acc[mr][nr];
                c = __builtin_amdgcn_mfma_f32_16x16x32_bf16(a0[mr], b0[nr], c, 0, 0, 0);
                c = __builtin_amdgcn_mfma_f32_16x16x32_bf16(a0[mr], b1[nr], c, 0, 0, 0);
                c = __builtin_amdgcn_mfma_f32_16x16x32_bf16(a1[mr], b0[nr], c, 0, 0, 0);
                acc[mr][nr] = c;
            }
        __syncthreads();
    }

    // ---- cross-ksub reduce (alias Ap as fp32 scratch: 4*1056*4B = 16.9KB) ----
    float* red = (float*)&Ap[0][0][0];
    if (ksub == 1) {
        #pragma unroll
        for (int mr = 0; mr < 2; ++mr)
            #pragma unroll
            for (int nr = 0; nr < 2; ++nr)
                #pragma unroll
                for (int r = 0; r < 4; ++r)
                    red[quad * 1056 + (mr * 16 + koff * 4 + r) * 33 + nr * 16 + l16] =
                        acc[mr][nr][r];
    }
    __syncthreads();
    if (ksub == 0) {
        #pragma unroll
        for (int mr = 0; mr < 2; ++mr)
            #pragma unroll
            for (int nr = 0; nr < 2; ++nr) {
                #pragma unroll
                for (int r = 0; r < 4; ++r)
                    acc[mr][nr][r] +=
                        red[quad * 1056 + (mr * 16 + koff * 4 + r) * 33 + nr * 16 + l16];
                #pragma unroll
                for (int r = 0; r < 4; ++r) {
                    int gr = row0 + wrow + mr * 16 + koff * 4 + r;
                    if (gr >= M) continue;
                    int gc = col0 + wcol + nr * 16 + l16;
                    float v = alpha * acc[mr][nr][r];
                    if (Out2) Out2[ob2 + (long)gr * ldo2 + gc] = v;
                    if (Cin) v += beta * Cin[cb + (long)gr * ldc + gc];
                    if (add_id && gr == gc) v += 1.f;
                    Out[ob + (long)gr * ldo + gc] = v;
                }
            }
    }
}

// ---- straight split: X (cnt fp32) -> 2 limb planes ----
__global__ void split_pl_k(const float* __restrict__ X, unsigned short* __restrict__ PS,
                           long cnt)
{
    long i = (long)blockIdx.x * 256 + threadIdx.x;
    if (i < cnt) split2(X[i], PS[i], PS[PLSZ + i]);
}

// ---- TSP: X [1024][1024] fp32 -> PS=planes(X), PT=planes(X^T), XT=fp32 X^T ----
__global__ void tsp_k(const float* __restrict__ X, unsigned short* __restrict__ PS,
                      unsigned short* __restrict__ PT, float* __restrict__ XT)
{
    __shared__ float t[32][33];
    const int tx = threadIdx.x & 31, ty4 = threadIdx.x >> 5;  // 256 thr: 8x(4 rows)
    const int r0 = blockIdx.x * 32, c0 = blockIdx.y * 32;
    #pragma unroll
    for (int i = 0; i < 4; ++i)
        t[ty4 * 4 + i][tx] = X[(long)(r0 + ty4 * 4 + i) * 1024 + c0 + tx];
    __syncthreads();
    if (PS) {
        #pragma unroll
        for (int i = 0; i < 4; ++i) {
            long idx = (long)(r0 + ty4 * 4 + i) * 1024 + c0 + tx;
            split2(t[ty4 * 4 + i][tx], PS[idx], PS[PLSZ + idx]);
        }
    }
    #pragma unroll
    for (int i = 0; i < 4; ++i) {
        float v = t[tx][ty4 * 4 + i];
        long idx = (long)(c0 + ty4 * 4 + i) * 1024 + r0 + tx;
        if (PT) split2(v, PT[idx], PT[PLSZ + idx]);
        if (XT) XT[idx] = v;
    }
}

// ---- transpose-scale(+id): out[r][c] = s*in[c][r] + (id && r==c); out R x C ----
__global__ void tr_scale_k(float* __restrict__ out, const float* __restrict__ in,
                           int R, int C, float s, int add_id)
{
    __shared__ float t[32][33];
    const int tx = threadIdx.x & 31, ty4 = threadIdx.x >> 5;
    const int r0 = blockIdx.x * 32, c0 = blockIdx.y * 32;   // over out tiles
    #pragma unroll
    for (int i = 0; i < 4; ++i)   // in rows = out cols (in is C x R)
        t[ty4 * 4 + i][tx] = in[(long)(c0 + ty4 * 4 + i) * R + r0 + tx];
    __syncthreads();
    #pragma unroll
    for (int i = 0; i < 4; ++i) {
        int r = r0 + ty4 * 4 + i, c = c0 + tx;
        float v = s * t[tx][ty4 * 4 + i];
        if (add_id && r == c) v += 1.f;
        out[(long)r * C + c] = v;
    }
}

// ---- Gcat planes: PG[n][k] = k<512 ? h*(V1T[k][n]-V2T[k][n]) : h*V2T[k-512][n] ----
__global__ void gtsp_k(const float* __restrict__ V1T, const float* __restrict__ V2T,
                       unsigned short* __restrict__ PG, float h)
{
    __shared__ float t[32][33];
    const int tx = threadIdx.x & 31, ty4 = threadIdx.x >> 5;
    const int k0 = blockIdx.x * 32, n0 = blockIdx.y * 32, z = blockIdx.z;
    #pragma unroll
    for (int i = 0; i < 4; ++i) {
        long idx = (long)(k0 + ty4 * 4 + i) * 1024 + n0 + tx;
        float v = (z == 0) ? h * (V1T[idx] - V2T[idx]) : h * V2T[idx];
        t[ty4 * 4 + i][tx] = v;
    }
    __syncthreads();
    #pragma unroll
    for (int i = 0; i < 4; ++i) {
        long idx = (long)(n0 + ty4 * 4 + i) * 1024 + z * 512 + k0 + tx;
        split2(t[tx][ty4 * 4 + i], PG[idx], PG[PLSZ + idx]);
    }
}

// dst[db + r*ds + c] = src[sb + r*ss + c]
__global__ void copy_rows_k(float* __restrict__ dst, long db, long ds,
                            const float* __restrict__ src, long sb, long ss, int ncols)
{
    int r = blockIdx.y;
    int c = blockIdx.x * 256 + threadIdx.x;
    if (c < ncols) dst[db + (long)r * ds + c] = src[sb + (long)r * ss + c];
}

// dst[db + r*ds + c] += src[r*ncols + c]
__global__ void add_rows_k(float* __restrict__ dst, long db, long ds,
                           const float* __restrict__ src, int ncols)
{
    int r = blockIdx.y;
    int c = blockIdx.x * 256 + threadIdx.x;
    if (c < ncols) dst[db + (long)r * ds + c] += src[(long)r * ncols + c];
}

__global__ void scale_add_id_k(float* __restrict__ dst, const float* __restrict__ src,
                               float s, int n)
{
    int r = blockIdx.y;
    int c = blockIdx.x * 256 + threadIdx.x;
    if (c < n) dst[(long)r * n + c] = s * src[(long)r * n + c] + ((r == c) ? 1.f : 0.f);
}

__global__ void scale_copy_k(float* __restrict__ dst, const float* __restrict__ src,
                             float s, long cnt)
{
    long i = (long)blockIdx.x * 256 + threadIdx.x;
    if (i < cnt) dst[i] = s * src[i];
}

__global__ void g1g2_k(float* __restrict__ g1, float* __restrict__ g2,
                       const float* __restrict__ v1, const float* __restrict__ v2,
                       float h, long cnt)
{
    long i = (long)blockIdx.x * 256 + threadIdx.x;
    if (i < cnt) {
        float a = v1[i], b = v2[i];
        g1[i] = h * (a - b);
        g2[i] = h * b;
    }
}

// ---------------------------------------------------------------------------
// FALLBACK GEMM (round-3, 3-limb, 30 MB ws) — used only if ws_size < 46 MB.
// ---------------------------------------------------------------------------
template <int BM, int BN, bool TRANSB>
__global__ __launch_bounds__(256) void gemm_mfma(
    const float* __restrict__ A, long ab, long lda,
    const float* __restrict__ B,
    const float* __restrict__ Cin, long cb, long ldc, float beta,
    float* __restrict__ Out, long ob, long ldo,
    int M, int Nn, int K, float alpha, int add_id)
{
    constexpr int LDT = 40;
    __shared__ unsigned short At[3][BM][LDT];
    __shared__ unsigned short Bt[3][BN][LDT];
    const int tid = threadIdx.x;
    const int lane = tid & 63;
    const int wid = tid >> 6;
    const int row0 = blockIdx.x * BM;
    const int col0 = blockIdx.y * BN;
    constexpr int MR = BM / 32;
    constexpr int NR = BN / 32;
    const int wrow = (wid >> 1) * (BM / 2);
    const int wcol = (wid & 1) * (BN / 2);
    const int l16 = lane & 15;
    const int koff = lane >> 4;
    f32x4 acc[MR][NR] = {};

    for (int k0 = 0; k0 < K; k0 += 32) {
        #pragma unroll
        for (int i = 0; i < BM / 32; ++i) {
            int r = i * 32 + (tid >> 3);
            int kl = (tid & 7) * 4;
            int gr = row0 + r;
            float4 v = make_float4(0.f, 0.f, 0.f, 0.f);
            if (gr < M) v = *(const float4*)&A[ab + (long)gr * lda + (k0 + kl)];
            unsigned short h0[4], h1[4], h2[4];
            split3(v.x, h0[0], h1[0], h2[0]);
            split3(v.y, h0[1], h1[1], h2[1]);
            split3(v.z, h0[2], h1[2], h2[2]);
            split3(v.w, h0[3], h1[3], h2[3]);
            *(ushort4*)&At[0][r][kl] = make_ushort4(h0[0], h0[1], h0[2], h0[3]);
            *(ushort4*)&At[1][r][kl] = make_ushort4(h1[0], h1[1], h1[2], h1[3]);
            *(ushort4*)&At[2][r][kl] = make_ushort4(h2[0], h2[1], h2[2], h2[3]);
        }
        if (TRANSB) {
            #pragma unroll
            for (int i = 0; i < BN / 32; ++i) {
                int r = i * 32 + (tid >> 3);
                int kl = (tid & 7) * 4;
                float4 v = *(const float4*)&B[(long)(col0 + r) * K + (k0 + kl)];
                unsigned short h0[4], h1[4], h2[4];
                split3(v.x, h0[0], h1[0], h2[0]);
                split3(v.y, h0[1], h1[1], h2[1]);
                split3(v.z, h0[2], h1[2], h2[2]);
                split3(v.w, h0[3], h1[3], h2[3]);
                *(ushort4*)&Bt[0][r][kl] = make_ushort4(h0[0], h0[1], h0[2], h0[3]);
                *(ushort4*)&Bt[1][r][kl] = make_ushort4(h1[0], h1[1], h1[2], h1[3]);
                *(ushort4*)&Bt[2][r][kl] = make_ushort4(h2[0], h2[1], h2[2], h2[3]);
            }
        } else {
            constexpr int TPK = BN / 4;
            #pragma unroll
            for (int i = 0; i < BN / 32; ++i) {
                int kl = i * (256 / TPK) + tid / TPK;
                int nl = (tid % TPK) * 4;
                float4 v = *(const float4*)&B[(long)(k0 + kl) * Nn + (col0 + nl)];
                unsigned short s0, s1, s2;
                split3(v.x, s0, s1, s2);
                Bt[0][nl + 0][kl] = s0; Bt[1][nl + 0][kl] = s1; Bt[2][nl + 0][kl] = s2;
                split3(v.y, s0, s1, s2);
                Bt[0][nl + 1][kl] = s0; Bt[1][nl + 1][kl] = s1; Bt[2][nl + 1][kl] = s2;
                split3(v.z, s0, s1, s2);
                Bt[0][nl + 2][kl] = s0; Bt[1][nl + 2][kl] = s1; Bt[2][nl + 2][kl] = s2;
                split3(v.w, s0, s1, s2);
                Bt[0][nl + 3][kl] = s0; Bt[1][nl + 3][kl] = s1; Bt[2][nl + 3][kl] = s2;
            }
        }
        __syncthreads();
        bf16x8 bf[NR][3];
        #pragma unroll
        for (int nr = 0; nr < NR; ++nr) {
            int brow = wcol + nr * 16 + l16;
            #pragma unroll
            for (int s = 0; s < 3; ++s)
                bf[nr][s] = *(const bf16x8*)&Bt[s][brow][koff * 8];
        }
        #pragma unroll
        for (int mr = 0; mr < MR; ++mr) {
            int arow = wrow + mr * 16 + l16;
            bf16x8 a0 = *(const bf16x8*)&At[0][arow][koff * 8];
            bf16x8 a1 = *(const bf16x8*)&At[1][arow][koff * 8];
            bf16x8 a2 = *(const bf16x8*)&At[2][arow][koff * 8];
            #pragma unroll
            for (int nr = 0; nr < NR; ++nr) {
                f32x4 c = acc[mr][nr];
                c = __builtin_amdgcn_mfma_f32_16x16x32_bf16(a0, bf[nr][0], c, 0, 0, 0);
                c = __builtin_amdgcn_mfma_f32_16x16x32_bf16(a0, bf[nr][1], c, 0, 0, 0);
                c = __builtin_amdgcn_mfma_f32_16x16x32_bf16(a1, bf[nr][0], c, 0, 0, 0);
                c = __builtin_amdgcn_mfma_f32_16x16x32_bf16(a0, bf[nr][2], c, 0, 0, 0);
                c = __builtin_amdgcn_mfma_f32_16x16x32_bf16(a1, bf[nr][1], c, 0, 0, 0);
                c = __builtin_amdgcn_mfma_f32_16x16x32_bf16(a2, bf[nr][0], c, 0, 0, 0);
                acc[mr][nr] = c;
            }
        }
        __syncthreads();
    }
    #pragma unroll
    for (int mr = 0; mr < MR; ++mr) {
        #pragma unroll
        for (int r = 0; r < 4; ++r) {
            int gr = row0 + wrow + mr * 16 + koff * 4 + r;
            if (gr >= M) continue;
            #pragma unroll
            for (int nr = 0; nr < NR; ++nr) {
                int gc = col0 + wcol + nr * 16 + l16;
                float v = alpha * acc[mr][nr][r];
                if (Cin) v += beta * Cin[cb + (long)gr * ldc + gc];
                if (add_id && gr == gc) v += 1.f;
                Out[ob + (long)gr * ldo + gc] = v;
            }
        }
    }
}

// ---------------------------------------------------------------------------
static void fallback_launch(void* const* d_in, void* d_out, void* d_ws,
                            hipStream_t stream)
{
    const float* y0 = (const float*)d_in[1];
    const float* u  = (const float*)d_in[2];
    const float* Am = (const float*)d_in[3];
    const float* Bm = (const float*)d_in[4];
    float* Yout = (float*)d_out;
    float* w = (float*)d_ws;
    const float h = 0.01f;
    const int N = GN;

    float* Eyy = w;
    float* T1  = Eyy + (long)N * N;
    float* T2  = T1  + (long)N * N;
    float* V1  = T2  + (long)N * N;
    float* Vt  = V1  + (long)N * GM;
    float* V2  = Vt  + (long)N * GM;
    float* G1  = V2  + (long)N * GM;
    float* G2  = G1  + (long)N * GM;
    float* Z   = G2  + (long)N * GM;
    float* Zt  = Z   + (long)CCH * N;
    dim3 blk(256);

    auto gemm = [&](bool transb, const float* A, long ab, long lda,
                    const float* B, const float* Cin, long cb, long ldc, float beta,
                    float* Out, long ob, long ldo,
                    int M, int Nn, int K, float alpha, int add_id) {
        if (M > 1536 && (Nn % 128) == 0) {
            dim3 grid((M + 127) / 128, Nn / 128);
            if (transb)
                gemm_mfma<128, 128, true><<<grid, blk, 0, stream>>>(A, ab, lda, B, Cin, cb, ldc, beta, Out, ob, ldo, M, Nn, K, alpha, add_id);
            else
                gemm_mfma<128, 128, false><<<grid, blk, 0, stream>>>(A, ab, lda, B, Cin, cb, ldc, beta, Out, ob, ldo, M, Nn, K, alpha, add_id);
        } else {
            dim3 grid((M + 63) / 64, Nn / 64);
            if (transb)
                gemm_mfma<64, 64, true><<<grid, blk, 0, stream>>>(A, ab, lda, B, Cin, cb, ldc, beta, Out, ob, ldo, M, Nn, K, alpha, add_id);
            else
                gemm_mfma<64, 64, false><<<grid, blk, 0, stream>>>(A, ab, lda, B, Cin, cb, ldc, beta, Out, ob, ldo, M, Nn, K, alpha, add_id);
        }
    };

    scale_add_id_k<<<dim3(4, N), blk, 0, stream>>>(T1, Am, h / 5.f, N);
    {
        float* pc = T1; float* pn = T2;
        for (int k = 4; k >= 1; --k) {
            float* out = (k == 1) ? Eyy : pn;
            gemm(false, Am, 0, N, pc, nullptr, 0, 0, 0.f, out, 0, N, N, N, N, h / (float)k, 1);
            pn = pc; pc = out;
        }
    }
    const long NM = (long)N * GM;
    scale_copy_k<<<dim3((unsigned)((NM + 255) / 256)), blk, 0, stream>>>(V1, Bm, 1.f / 120.f, NM);
    {
        const float f1[4] = {1.f / 24.f, 1.f / 6.f, 0.5f, 1.f};
        float* pc = V1; float* pn = Vt;
        for (int j = 3; j >= 0; --j) {
            gemm(false, Am, 0, N, pc, Bm, 0, GM, f1[3 - j], pn, 0, GM, N, GM, N, h, 0);
            float* t = pc; pc = pn; pn = t;
        }
    }
    scale_copy_k<<<dim3((unsigned)((NM + 255) / 256)), blk, 0, stream>>>(V2, Bm, 1.f / 720.f, NM);
    {
        const float f2[4] = {1.f / 120.f, 1.f / 24.f, 1.f / 6.f, 0.5f};
        float* pc = V2; float* pn = Vt;
        for (int j = 3; j >= 0; --j) {
            gemm(false, Am, 0, N, pc, Bm, 0, GM, f2[3 - j], pn, 0, GM, N, GM, N, h, 0);
            float* t = pc; pc = pn; pn = t;
        }
    }
    g1g2_k<<<dim3((unsigned)((NM + 255) / 256)), blk, 0, stream>>>(G1, G2, V1, V2, h, NM);
    gemm(true, u, 0, GM, G1, nullptr, 0, 0, 0.f, Yout, (long)N, N, GT - 1, N, GM, 1.f, 0);
    gemm(true, u, GM, GM, G2, Yout, (long)N, N, 1.f, Yout, (long)N, N, GT - 1, N, GM, 1.f, 0);
    copy_rows_k<<<dim3(4, 1), blk, 0, stream>>>(Yout, 0, 0, y0, 0, 0, N);
    for (int s = 2; s <= SCH; ++s) {
        int Mr = (GT - 1 - s) / SCH + 1;
        gemm(true, Yout, (long)(s - 1) * N, (long)SCH * N, Eyy,
             Yout, (long)s * N, (long)SCH * N, 1.f,
             Yout, (long)s * N, (long)SCH * N, Mr, N, N, 1.f, 0);
    }
    copy_rows_k<<<dim3(4, 1), blk, 0, stream>>>(Z, 0, 0, y0, 0, 0, N);
    copy_rows_k<<<dim3(4, CCH - 1), blk, 0, stream>>>(Z, (long)N, (long)N,
                                                      Yout, (long)SCH * N, (long)SCH * N, N);
    gemm(false, Eyy, 0, N, Eyy, nullptr, 0, 0, 0.f, T1, 0, N, N, N, N, 1.f, 0);
    gemm(false, T1, 0, N, T1, nullptr, 0, 0, 0.f, T2, 0, N, N, N, N, 1.f, 0);
    gemm(false, T2, 0, N, T2, nullptr, 0, 0, 0.f, T1, 0, N, N, N, N, 1.f, 0);
    {
        float* Mc = T1; float* Mo = T2;
        float* Zc = Z;  float* Zn = Zt;
        for (int p = 0; p < 10; ++p) {
            int o = 1 << p;
            gemm(true, Zc, 0, N, Mc, Zc, (long)o * N, N, 1.f,
                 Zn, (long)o * N, N, CCH - o, N, N, 1.f, 0);
            copy_rows_k<<<dim3(4, o), blk, 0, stream>>>(Zn, 0, N, Zc, 0, N, N);
            if (p < 9) {
                gemm(false, Mc, 0, N, Mc, nullptr, 0, 0, 0.f, Mo, 0, N, N, N, N, 1.f, 0);
                float* t = Mc; Mc = Mo; Mo = t;
            }
            float* t = Zc; Zc = Zn; Zn = t;
        }
        copy_rows_k<<<dim3(4, CCH), blk, 0, stream>>>(Yout, 0, (long)SCH * N, Zc, 0, N, N);
        float* Q = Zc; float* Qt = Zn;
        for (int s = 1; s <= SCH - 1; ++s) {
            gemm(true, Q, 0, N, Eyy, nullptr, 0, 0, 0.f, Qt, 0, N, CCH, N, N, 1.f, 0);
            int Mr = (GT - 1 - s) / SCH + 1;
            add_rows_k<<<dim3(4, Mr), blk, 0, stream>>>(Yout, (long)s * N, (long)SCH * N, Qt, N);
            float* t = Q; Q = Qt; Qt = t;
        }
    }
}

// ---------------------------------------------------------------------------
extern "C" void kernel_launch(void* const* d_in, const int* in_sizes, int n_in,
                              void* d_out, int out_size, void* d_ws, size_t ws_size,
                              hipStream_t stream)
{
    (void)in_sizes; (void)n_in; (void)out_size;
    const size_t NEED = 46ull * 1024 * 1024;
    if (ws_size < NEED) {                      // safety: round-3 path (30 MB)
        fallback_launch(d_in, d_out, d_ws, stream);
        return;
    }

    const float* y0 = (const float*)d_in[1];
    const float* u  = (const float*)d_in[2];
    const float* Am = (const float*)d_in[3];
    const float* Bm = (const float*)d_in[4];
    float* Yout = (float*)d_out;               // (8192 x 1024) fp32
    char* w = (char*)d_ws;

    const float h = 0.01f;
    const size_t MB = 1024 * 1024;

    unsigned short* PA  = (unsigned short*)(w + 0 * MB);   // planes(Am)       4MB
    unsigned short* PE  = (unsigned short*)(w + 4 * MB);   // planes(Eyy)      4MB
    unsigned short* PWT = (unsigned short*)(w + 8 * MB);   // planes(W^T)      4MB
    unsigned short* PW  = (unsigned short*)(w + 12 * MB);  // planes(W)        4MB
    unsigned short* PG  = (unsigned short*)(w + 16 * MB);  // planes(Gcat)     4MB
    float* T1   = (float*)(w + 20 * MB);                   // fp32 ping        4MB
    float* T2   = (float*)(w + 24 * MB);                   // fp32 pong        4MB
    float* EyyT = (float*)(w + 28 * MB);                   // -> reused as Wf1
    float* Wf0  = (float*)(w + 32 * MB);
    float* Zc0  = (float*)(w + 36 * MB);
    float* Zn0  = (float*)(w + 40 * MB);
    float* BmT  = (float*)(w + 44 * MB);                   // 2MB (512x1024)
    float* Wf1  = EyyT;

    dim3 blk(256), blk5(512);
    dim3 tgrid(32, 32);                        // 1024/32 tiles

    // gemm_ps wrapper: K=1024, Nn=1024 fixed
    auto G = [&](const float* Dyn, long ab, long lda, const unsigned short* S,
                 const float* Cin, long cb, long ldc, float beta,
                 float* Out, long ob, long ldo,
                 float* Out2, long ob2, long ldo2,
                 int M, float alpha, int add_id) {
        dim3 grid((M + 63) / 64, 16);
        gemm_ps<<<grid, blk5, 0, stream>>>(Dyn, ab, lda, S, Cin, cb, ldc, beta,
                                           Out, ob, ldo, Out2, ob2, ldo2, M, alpha, add_id);
    };

    // ---- planes(Am) ----
    split_pl_k<<<dim3(4096), blk, 0, stream>>>(Am, PA, (long)PLSZ);

    // ---- expm in transposed space: P^T_5 = I + (h/5)A^T; P^T_k = I + (h/k) P^T @ A^T ----
    tr_scale_k<<<tgrid, blk, 0, stream>>>(T1, Am, 1024, 1024, h / 5.f, 1);
    {
        float* pc = T1; float* pn = T2;
        for (int k = 4; k >= 1; --k) {
            float* out = (k == 1) ? EyyT : pn;
            G(pc, 0, 1024, PA, nullptr, 0, 0, 0.f, out, 0, 1024, nullptr, 0, 0,
              1024, h / (float)k, 1);
            pn = pc; pc = out;
        }
    }
    // ---- TSP(EyyT): PS=planes(EyyT)=planes(W0^T), PT=planes(Eyy), fp32T=Eyy=W0 ----
    tsp_k<<<tgrid, blk, 0, stream>>>(EyyT, PWT, PE, Wf0);

    // ---- phi chains in transposed space (M=512): V^T = h*V^T@A^T + f*B^T ----
    tr_scale_k<<<dim3(16, 32), blk, 0, stream>>>(BmT, Bm, 512, 1024, 1.f, 0);
    float* V1a = T1; float* V1b = T1 + 512 * 1024;
    float* V2a = T2; float* V2b = T2 + 512 * 1024;
    const long NM = 512 * 1024;
    scale_copy_k<<<dim3((unsigned)((NM + 255) / 256)), blk, 0, stream>>>(V1a, BmT, 1.f / 120.f, NM);
    scale_copy_k<<<dim3((unsigned)((NM + 255) / 256)), blk, 0, stream>>>(V2a, BmT, 1.f / 720.f, NM);
    {
        const float f1[4] = {1.f / 24.f, 1.f / 6.f, 0.5f, 1.f};
        const float f2[4] = {1.f / 120.f, 1.f / 24.f, 1.f / 6.f, 0.5f};
        float* c1 = V1a; float* n1 = V1b;
        float* c2 = V2a; float* n2 = V2b;
        for (int j = 0; j < 4; ++j) {
            G(c1, 0, 1024, PA, BmT, 0, 1024, f1[j], n1, 0, 1024, nullptr, 0, 0, 512, h, 0);
            G(c2, 0, 1024, PA, BmT, 0, 1024, f2[j], n2, 0, 1024, nullptr, 0, 0, 512, h, 0);
            float* t = c1; c1 = n1; n1 = t;
            t = c2; c2 = n2; n2 = t;
        }  // 4 swaps -> finals in V1a, V2a
    }
    // ---- planes(Gcat) from V1^T, V2^T ----
    gtsp_k<<<dim3(16, 32, 2), blk, 0, stream>>>(V1a, V2a, PG, h);

    // ---- c-staging: Yout[t] = [u_{t-1}|u_t] @ Gcat^T, t=1..8191 (one GEMM, K=1024) ----
    G(u, 0, 512, PG, nullptr, 0, 0, 0.f, Yout, 1024, 1024, nullptr, 0, 0, GT - 1, 1.f, 0);
    copy_rows_k<<<dim3(4, 1), blk, 0, stream>>>(Yout, 0, 0, y0, 0, 0, 1024);

    // ---- phase 1: within-chunk responses, in place (rows ≡ s get rows ≡ s-1 @ Eyy^T) ----
    for (int s = 2; s <= SCH; ++s) {
        int Mr = (s <= 7) ? 1024 : 1023;
        G(Yout, (long)(s - 1) * 1024, 8192, PE,
          Yout, (long)s * 1024, 8192, 1.f,
          Yout, (long)s * 1024, 8192, nullptr, 0, 0, Mr, 1.f, 0);
    }

    // ---- phase 2: boundary doubling with W_p = E^(8*2^p) ----
    copy_rows_k<<<dim3(4, 1), blk, 0, stream>>>(Zc0, 0, 0, y0, 0, 0, 1024);
    copy_rows_k<<<dim3(4, CCH - 1), blk, 0, stream>>>(Zc0, 1024, 1024,
                                                      Yout, (long)SCH * 1024, (long)SCH * 1024, 1024);
    // W0 = Eyy (Wf0); planes(W0) = PE; planes(W0^T) = PWT. First 3 squarings reach E^8,
    // but doubling needs W_p = E^(8*2^p): round p uses E^(2^(p+3)); we instead fold the
    // first 3 squarings into rounds by starting the doubling at "virtual offset" —
    // equivalent simple form: square to E^8 first, then 10 rounds as before.
    {
        float* Wc = Wf0; float* Wn = Wf1;
        const unsigned short* SPW = PE;        // planes(W current)
        // 3 squarings: E -> E^2 -> E^4 -> E^8
        for (int q = 0; q < 3; ++q) {
            G(Wc, 0, 1024, PWT, nullptr, 0, 0, 0.f, Wn, 0, 1024, nullptr, 0, 0, 1024, 1.f, 0);
            tsp_k<<<tgrid, blk, 0, stream>>>(Wn, PW, PWT, nullptr);
            float* t = Wc; Wc = Wn; Wn = t;
            SPW = PW;
        }
        float* Zc = Zc0; float* Zn = Zn0;
        for (int p = 0; p < 10; ++p) {
            int o = 1 << p;
            // Zn[i] = Zc[i] + Zc[i-o] @ W^T   (i in [o, 1024))
            G(Zc, 0, 1024, SPW, Zc, (long)o * 1024, 1024, 1.f,
              Zn, (long)o * 1024, 1024, nullptr, 0, 0, 1024 - o, 1.f, 0);
            copy_rows_k<<<dim3(4, o), blk, 0, stream>>>(Zn, 0, 1024, Zc, 0, 1024, 1024);
            if (p < 9) {
                G(Wc, 0, 1024, PWT, nullptr, 0, 0, 0.f, Wn, 0, 1024, nullptr, 0, 0, 1024, 1.f, 0);
                tsp_k<<<tgrid, blk, 0, stream>>>(Wn, PW, PWT, nullptr);
                float* t = Wc; Wc = Wn; Wn = t;
                SPW = PW;
            }
            float* t = Zc; Zc = Zn; Zn = t;
        }
        // ---- phase 3: y_{8i} = z_i exact; y_{8i+s} += E^s z_i, s=1..7 ----
        copy_rows_k<<<dim3(4, CCH), blk, 0, stream>>>(Yout, 0, (long)SCH * 1024, Zc, 0, 1024, 1024);
        float* Q = Zc; float* Qt = Zn;
        for (int s = 1; s <= SCH - 1; ++s) {
            // Yout[8i+s] += Q[i] @ Eyy^T ; Qt[i] = Q[i] @ Eyy^T (pure)
            G(Q, 0, 1024, PE,
              Yout, (long)s * 1024, 8192, 1.f,
              Yout, (long)s * 1024, 8192,
              Qt, 0, 1024, 1024, 1.f, 0);
            float* t = Q; Q = Qt; Qt = t;
        }
    }
}